// Round 11
// baseline (750.641 us; speedup 1.0000x reference)
//
#include <hip/hip_runtime.h>
#include <stdint.h>

#define B_SZ 8192
static const size_t BH = (size_t)B_SZ * 512;

typedef short bfrag8 __attribute__((ext_vector_type(8)));
typedef float f32x4 __attribute__((ext_vector_type(4)));

__device__ __forceinline__ unsigned short f2bf(float f) {
  union { float f; uint32_t u; } c; c.f = f;
  uint32_t u = c.u;
  uint32_t r = (u + 0x7FFFu + ((u >> 16) & 1u)) >> 16;
  return (unsigned short)r;
}
__device__ __forceinline__ float bf2f(unsigned short u) {
  union { uint32_t u; float f; } c; c.u = ((uint32_t)u) << 16;
  return c.f;
}
// packed f32x2 -> bf16x2 (RNE), single HW instruction
__device__ __forceinline__ uint32_t pk2(float a, float b) {
  uint32_t r;
  asm("v_cvt_pk_bf16_f32 %0, %1, %2" : "=v"(r) : "v"(a), "v"(b));
  return r;
}
__device__ __forceinline__ float sigm(float x) { return 1.0f / (1.0f + __expf(-x)); }
__device__ __forceinline__ float tanh_fast(float x) {
  float cx = fminf(fmaxf(x, -15.0f), 15.0f);
  float e = __expf(2.0f * cx);
  return (e - 1.0f) / (e + 1.0f);
}

__device__ __forceinline__ void gload16(const void* g, void* l) {
  __builtin_amdgcn_global_load_lds(
      (const __attribute__((address_space(1))) void*)g,
      (__attribute__((address_space(3))) void*)l, 16, 0, 0);
}

// bijective XCD-chunk swizzle (m204)
__device__ __forceinline__ void xcd_swizzle(int& bx, int& by, int& bz) {
  int nx = gridDim.x, ny = gridDim.y, nz = gridDim.z;
  int nwg = nx * ny * nz;
  int id = blockIdx.x + nx * (blockIdx.y + ny * blockIdx.z);
  int q = nwg >> 3, r = nwg & 7;
  int xcd = id & 7, lin = id >> 3;
  int swz = (xcd < r ? xcd * (q + 1) : r * (q + 1) + (xcd - r) * q) + lin;
  bx = swz % nx; swz /= nx;
  by = swz % ny; bz = swz / ny;
}

// ======== ph/pc GEMM: 128x256 tile, 2-phase, 8 waves, f32-A reg-staged ======
// out[row,col] = sum_s A_s[row,:512](f32) @ B[col, co_s:+512]^T + bias
// LDS 96KB: A dbuf @0/16K (128x64 bf16 = 16K), B dbuf @32K/64K (256x64 = 32K).
struct P8Job {
  const float* A[3];
  int co[3];
  int nseg;
  const unsigned short* B;
  const float* bias;
  unsigned short* outBf;
};
struct P8Args {
  P8Job j[4];
  int ldB, outStride;
};

__global__ __launch_bounds__(512, 1) void pgemm256_k(P8Args pa) {
  extern __shared__ char lds[];
  int bx, by, bz;
  xcd_swizzle(bx, by, bz);
  const P8Job jb = pa.j[bz];
  const int tid = threadIdx.x;
  const int lane = tid & 63;
  const int wv = tid >> 6;
  const int wr = wv >> 2, wc = wv & 3;  // 2 M-groups x 4 N-groups
  const int m0 = by * 128;

  // B staging: 4 chunks/thread (256 rows x 8 slots)
  int cgB[4];
  const char* bPtr[4];
#pragma unroll
  for (int q = 0; q < 4; ++q) {
    int cl = q * 512 + tid;
    int row = cl >> 3, cs = cl & 7;
    cgB[q] = cs ^ (row & 7);
    bPtr[q] = (const char*)jb.B + (size_t)(bx * 256 + row) * pa.ldB * 2;
  }
  // A staging: 2 chunks/thread (128 rows x 8 slots)
  int rowA[2], cgA[2];
#pragma unroll
  for (int q = 0; q < 2; ++q) {
    int cl = q * 512 + tid;
    int row = cl >> 3, cs = cl & 7;
    cgA[q] = cs ^ (row & 7);
    rowA[q] = row;
  }

  auto stageB = [&](int t, int buf) {
    int seg = t >> 3, k0 = (t & 7) << 6;
    int coB = (jb.co[seg] + k0) * 2;
    char* Bb = lds + 32768 + buf * 32768;
#pragma unroll
    for (int q = 0; q < 4; ++q)
      gload16(bPtr[q] + coB + cgB[q] * 16, Bb + (q * 512 + tid) * 16);
  };
  auto loadA = [&](int t, float4* a0, float4* a1) {
    int seg = t >> 3, k0 = (t & 7) << 6;
    const float* Ab = jb.A[seg];
#pragma unroll
    for (int q = 0; q < 2; ++q) {
      const float4* p = (const float4*)(Ab + (size_t)(m0 + rowA[q]) * 512 + k0 +
                                        cgA[q] * 8);
      a0[q] = p[0];
      a1[q] = p[1];
    }
  };
  auto writeA = [&](const float4* a0, const float4* a1, int buf) {
    char* Ab = lds + buf * 16384;
#pragma unroll
    for (int q = 0; q < 2; ++q) {
      uint4 w;
      w.x = pk2(a0[q].x, a0[q].y);
      w.y = pk2(a0[q].z, a0[q].w);
      w.z = pk2(a1[q].x, a1[q].y);
      w.w = pk2(a1[q].z, a1[q].w);
      *(uint4*)(Ab + (q * 512 + tid) * 16) = w;
    }
  };

  f32x4 acc[4][4];
#pragma unroll
  for (int a = 0; a < 4; ++a)
#pragma unroll
    for (int b = 0; b < 4; ++b) acc[a][b] = f32x4{0.f, 0.f, 0.f, 0.f};

  const int nt = jb.nseg * 8;

  // prologue: stage tile 0
  {
    float4 a0[2], a1[2];
    stageB(0, 0);
    loadA(0, a0, a1);
    writeA(a0, a1, 0);
  }
  __syncthreads();

  int cur = 0;
  for (int t = 0; t < nt; ++t) {
    float4 a0[2], a1[2];
    const bool more = (t + 1 < nt);
    if (more) {
      stageB(t + 1, cur ^ 1);   // oldest in queue
      loadA(t + 1, a0, a1);     // newest; writeA's implicit wait drains both
    }
    const char* As = lds + cur * 16384;
    const char* Bs = lds + 32768 + cur * 32768;
    bfrag8 bfr[4][2];
#pragma unroll
    for (int nf = 0; nf < 4; ++nf)
#pragma unroll
      for (int ks = 0; ks < 2; ++ks) {
        int row = wc * 64 + nf * 16 + (lane & 15);
        bfr[nf][ks] = *(const bfrag8*)(Bs + row * 128 +
                                       (((ks * 4 + (lane >> 4)) ^ (row & 7)) * 16));
      }
#pragma unroll
    for (int mf = 0; mf < 4; ++mf) {
      bfrag8 af[2];
#pragma unroll
      for (int ks = 0; ks < 2; ++ks) {
        int row = wr * 64 + mf * 16 + (lane & 15);
        af[ks] = *(const bfrag8*)(As + row * 128 +
                                  (((ks * 4 + (lane >> 4)) ^ (row & 7)) * 16));
      }
#pragma unroll
      for (int nf = 0; nf < 4; ++nf)
#pragma unroll
        for (int ks = 0; ks < 2; ++ks)
          acc[mf][nf] = __builtin_amdgcn_mfma_f32_16x16x32_bf16(
              af[ks], bfr[nf][ks], acc[mf][nf], 0, 0, 0);
    }
    if (more) writeA(a0, a1, cur ^ 1);  // HBM latency hidden under MFMA
    __syncthreads();
    cur ^= 1;
  }

  const int c4 = lane & 15;
  const int r4 = lane >> 4;
  const int n0 = bx * 256;
#pragma unroll
  for (int nf = 0; nf < 4; ++nf) {
    int colg = n0 + wc * 64 + nf * 16 + c4;
    float bv = jb.bias[colg];
#pragma unroll
    for (int mf = 0; mf < 4; ++mf)
#pragma unroll
      for (int r = 0; r < 4; ++r) {
        int rowg = m0 + wr * 64 + mf * 16 + r4 * 4 + r;
        jb.outBf[(size_t)rowg * pa.outStride + colg] = f2bf(acc[mf][nf][r] + bv);
      }
  }
}

// ------- gates GEMM: 256x256 tile, counted-vmcnt 2-phase, 8 waves -----------
struct GJob {
  const unsigned short* ph;
  const unsigned short* Whh;
  const unsigned short* pc;  // bf16
  float* gh; float* gc;
  int cell, last;
};
struct GArgs {
  GJob j[2];
  const float* x;
  const float* W_ih; const float* b_ih; const float* b_hh;
  const float* h_ext; const float* c_ext;
  float* fh; float* fc;
  unsigned short* finalB;
};

__global__ __launch_bounds__(512, 2) void gates_k(GArgs ga) {
  extern __shared__ char lds[];
  int bx, by, bz;
  xcd_swizzle(bx, by, bz);
  const GJob jb = ga.j[bz];
  const int tid = threadIdx.x;
  const int lane = tid & 63;
  const int wv = tid >> 6;
  const int wr = wv >> 2;
  const int wc = wv & 3;
  const int m0 = by * 256;

  int rowS[4], cgS[4];
  const char* bPtr[4];
#pragma unroll
  for (int q = 0; q < 4; ++q) {
    int cl = q * 512 + tid;
    int row = cl >> 3, cs = cl & 7;
    cgS[q] = cs ^ (row & 7);
    rowS[q] = row;
    int browG = ((row >> 4) & 3) * 512 + bx * 64 + ((row >> 6) << 4) + (row & 15);
    bPtr[q] = (const char*)jb.Whh + (size_t)browG * 512 * 2;
  }

  auto stage = [&](int t, int buf) {
    int k0 = t << 6;
    char* Ab = lds + buf * 32768;
    char* Bb = lds + 65536 + buf * 32768;
#pragma unroll
    for (int q = 0; q < 4; ++q)
      gload16((const char*)jb.ph + ((size_t)(m0 + rowS[q]) * 512 + k0) * 2 + cgS[q] * 16,
              Ab + (q * 512 + tid) * 16);
#pragma unroll
    for (int q = 0; q < 4; ++q)
      gload16(bPtr[q] + k0 * 2 + cgS[q] * 16, Bb + (q * 512 + tid) * 16);
  };

  f32x4 acc[8][4];
#pragma unroll
  for (int a = 0; a < 8; ++a)
#pragma unroll
    for (int b = 0; b < 4; ++b) acc[a][b] = f32x4{0.f, 0.f, 0.f, 0.f};

  stage(0, 0);
  int cur = 0;
  for (int t = 0; t < 8; ++t) {
    if (t + 1 < 8) {
      stage(t + 1, cur ^ 1);
      asm volatile("s_waitcnt vmcnt(8)" ::: "memory");  // tile t landed; t+1 in flight
    } else {
      asm volatile("s_waitcnt vmcnt(0)" ::: "memory");
    }
    __builtin_amdgcn_s_barrier();
    asm volatile("" ::: "memory");
    const char* As = lds + cur * 32768;
    const char* Bs = lds + 65536 + cur * 32768;
    bfrag8 bfr[4][2];
#pragma unroll
    for (int nf = 0; nf < 4; ++nf)
#pragma unroll
      for (int ks = 0; ks < 2; ++ks) {
        int row = wc * 64 + nf * 16 + (lane & 15);
        bfr[nf][ks] = *(const bfrag8*)(Bs + row * 128 +
                                       (((ks * 4 + (lane >> 4)) ^ (row & 7)) * 16));
      }
#pragma unroll
    for (int mf = 0; mf < 8; ++mf) {
      bfrag8 af[2];
#pragma unroll
      for (int ks = 0; ks < 2; ++ks) {
        int row = wr * 128 + mf * 16 + (lane & 15);
        af[ks] = *(const bfrag8*)(As + row * 128 +
                                  (((ks * 4 + (lane >> 4)) ^ (row & 7)) * 16));
      }
#pragma unroll
      for (int nf = 0; nf < 4; ++nf)
#pragma unroll
        for (int ks = 0; ks < 2; ++ks)
          acc[mf][nf] = __builtin_amdgcn_mfma_f32_16x16x32_bf16(
              af[ks], bfr[nf][ks], acc[mf][nf], 0, 0, 0);
    }
    __builtin_amdgcn_sched_barrier(0);  // pin reads/MFMA before reuse barrier
    __builtin_amdgcn_s_barrier();       // reads done before next stage overwrite
    asm volatile("" ::: "memory");
    cur ^= 1;
  }

  const int c4 = lane & 15;
  const int r4 = lane >> 4;
  int hcol = bx * 64 + wc * 16 + c4;
  const float* Wih = ga.W_ih + jb.cell * 2048;
  const float* bih = ga.b_ih + jb.cell * 2048;
  const float* bhh = ga.b_hh + jb.cell * 2048;
  float wih[4], gb[4];
#pragma unroll
  for (int q = 0; q < 4; ++q) {
    wih[q] = Wih[q * 512 + hcol];
    gb[q] = bih[q * 512 + hcol] + bhh[q * 512 + hcol];
  }
#pragma unroll
  for (int mf = 0; mf < 8; ++mf)
#pragma unroll
    for (int r = 0; r < 4; ++r) {
      int b = m0 + wr * 128 + mf * 16 + r4 * 4 + r;
      float xi = ga.x[b * 8 + jb.cell];
      float vi = acc[mf][0][r] + xi * wih[0] + gb[0];
      float vf = acc[mf][1][r] + xi * wih[1] + gb[1];
      float vg = acc[mf][2][r] + xi * wih[2] + gb[2];
      float vo = acc[mf][3][r] + xi * wih[3] + gb[3];
      size_t o = (size_t)b * 512 + hcol;
      float pcv = bf2f(jb.pc[o]);
      float cn = sigm(vf) * pcv + sigm(vi) * tanh_fast(vg);
      float hn = sigm(vo) * tanh_fast(cn);
      jb.gh[o] = hn;
      jb.gc[o] = cn;
      if (jb.last) {
        float fh = hn + ga.h_ext[o];
        float fc = cn + ga.c_ext[o];
        ga.fh[o] = fh;
        ga.fc[o] = fc;
        ga.finalB[(size_t)b * 1024 + hcol] = f2bf(fh);
        ga.finalB[(size_t)b * 1024 + 512 + hcol] = f2bf(fc);
      }
    }
}

// ================= legacy 128x128 2-barrier GEMM (FC1 only) =================
struct PJob {
  const void* A[3];
  int co[3];
  int nseg, relu;
  const unsigned short* B;
  const float* bias;
  unsigned short* outBf;
};
struct PArgs {
  PJob j[8];
  int ldA, ldB, outStride;
};

__global__ __launch_bounds__(256, 4) void pgemm_k(PArgs pa) {
  __shared__ __align__(16) char As[16384];
  __shared__ __align__(16) char Bs[16384];
  int bx, by, bz;
  xcd_swizzle(bx, by, bz);
  const PJob jb = pa.j[bz];
  const int tid = threadIdx.x;
  const int lane = tid & 63;
  const int wv = tid >> 6;
  const int wr = wv >> 1, wc = wv & 1;
  const int m0 = by * 128;

  int rowA[4], cg[4];
  const char* browPtr[4];
#pragma unroll
  for (int q = 0; q < 4; ++q) {
    int cl = q * 256 + tid;
    int row = cl >> 3, cs = cl & 7;
    cg[q] = cs ^ (row & 7);
    rowA[q] = row;
    browPtr[q] = (const char*)jb.B + (size_t)(bx * 128 + row) * pa.ldB * 2;
  }

  f32x4 acc[4][4];
#pragma unroll
  for (int a = 0; a < 4; ++a)
#pragma unroll
    for (int b = 0; b < 4; ++b) acc[a][b] = f32x4{0.f, 0.f, 0.f, 0.f};

  for (int s = 0; s < jb.nseg; ++s) {
    const char* Abase = (const char*)jb.A[s];
    const int coB = jb.co[s] * 2;
    for (int k0 = 0; k0 < 512; k0 += 64) {
#pragma unroll
      for (int q = 0; q < 4; ++q)
        gload16(Abase + ((size_t)(m0 + rowA[q]) * pa.ldA + k0) * 2 + cg[q] * 16,
                As + (q * 256 + tid) * 16);
#pragma unroll
      for (int q = 0; q < 4; ++q)
        gload16(browPtr[q] + coB + k0 * 2 + cg[q] * 16,
                Bs + (q * 256 + tid) * 16);
      __syncthreads();
#pragma unroll
      for (int ks = 0; ks < 2; ++ks) {
        bfrag8 af[4], bfr[4];
#pragma unroll
        for (int mf = 0; mf < 4; ++mf) {
          int row = wr * 64 + mf * 16 + (lane & 15);
          af[mf] = *(const bfrag8*)(As + row * 128 +
                                    ((ks * 4 + (lane >> 4)) ^ (row & 7)) * 16);
        }
#pragma unroll
        for (int nf = 0; nf < 4; ++nf) {
          int row = wc * 64 + nf * 16 + (lane & 15);
          bfr[nf] = *(const bfrag8*)(Bs + row * 128 +
                                     ((ks * 4 + (lane >> 4)) ^ (row & 7)) * 16);
        }
#pragma unroll
        for (int mf = 0; mf < 4; ++mf)
#pragma unroll
          for (int nf = 0; nf < 4; ++nf)
            acc[mf][nf] = __builtin_amdgcn_mfma_f32_16x16x32_bf16(
                af[mf], bfr[nf], acc[mf][nf], 0, 0, 0);
      }
      __syncthreads();
    }
  }

  const int c4 = lane & 15;
  const int r4 = lane >> 4;
  const int n0 = bx * 128;
#pragma unroll
  for (int nf = 0; nf < 4; ++nf) {
    int colg = n0 + wc * 64 + nf * 16 + c4;
    float bv = jb.bias[colg];
#pragma unroll
    for (int mf = 0; mf < 4; ++mf)
#pragma unroll
      for (int r = 0; r < 4; ++r) {
        int rowg = m0 + wr * 64 + mf * 16 + r4 * 4 + r;
        size_t o = (size_t)rowg * pa.outStride + colg;
        float v = acc[mf][nf][r] + bv;
        if (jb.relu) v = fmaxf(v, 0.0f);
        jb.outBf[o] = f2bf(v);
      }
  }
}

// ---------------- one-shot f32 -> bf16 converter (weights only) -------------
struct CvtArgs {
  const float4* s[8];
  uint2* d[8];
  long start[9];
};
__global__ __launch_bounds__(256) void convert_many(CvtArgs ca) {
  long total = ca.start[8];
  long stride = (long)gridDim.x * blockDim.x;
  for (long idx = (long)blockIdx.x * blockDim.x + threadIdx.x; idx < total;
       idx += stride) {
    int jb = 0;
#pragma unroll
    for (int q = 1; q < 8; ++q) jb += (idx >= ca.start[q]) ? 1 : 0;
    long local = idx - ca.start[jb];
    float4 v = ca.s[jb][local];
    uint2 o;
    o.x = (uint32_t)f2bf(v.x) | ((uint32_t)f2bf(v.y) << 16);
    o.y = (uint32_t)f2bf(v.z) | ((uint32_t)f2bf(v.w) << 16);
    ca.d[jb][local] = o;
  }
}

__global__ __launch_bounds__(256)
void fc2_kernel(const unsigned short* hid, const float* W2, const float* b2,
                float* outlin) {
  int row = blockIdx.x * 4 + (threadIdx.x >> 6);
  int lane = threadIdx.x & 63;
  uint2 hv = ((const uint2*)(hid + (size_t)row * 256))[lane];
  float4 wv = ((const float4*)W2)[lane];
  float s = bf2f((unsigned short)(hv.x & 0xffffu)) * wv.x +
            bf2f((unsigned short)(hv.x >> 16)) * wv.y +
            bf2f((unsigned short)(hv.y & 0xffffu)) * wv.z +
            bf2f((unsigned short)(hv.y >> 16)) * wv.w;
#pragma unroll
  for (int o = 32; o > 0; o >>= 1) s += __shfl_down(s, o);
  if (lane == 0) outlin[row] = s + b2[0];
}

__global__ __launch_bounds__(1024)
void bn_kernel(const float* outlin, const float* gamma, const float* beta,
               float* out) {
  __shared__ float sred[16], sred2[16];
  __shared__ float smu, srs;
  float s = 0.f, s2 = 0.f;
  for (int i = threadIdx.x; i < 8192; i += 1024) {
    float v = outlin[i];
    s += v; s2 += v * v;
  }
#pragma unroll
  for (int o = 32; o > 0; o >>= 1) { s += __shfl_down(s, o); s2 += __shfl_down(s2, o); }
  if ((threadIdx.x & 63) == 0) { sred[threadIdx.x >> 6] = s; sred2[threadIdx.x >> 6] = s2; }
  __syncthreads();
  if (threadIdx.x == 0) {
    float S = 0.f, S2 = 0.f;
    for (int q = 0; q < 16; ++q) { S += sred[q]; S2 += sred2[q]; }
    float mu = S * (1.0f / 8192.0f);
    float var = S2 * (1.0f / 8192.0f) - mu * mu;
    smu = mu; srs = rsqrtf(var + 1e-5f);
  }
  __syncthreads();
  float gm = gamma[0], bt = beta[0];
  for (int i = threadIdx.x; i < 8192; i += 1024) {
    float v = (outlin[i] - smu) * srs * gm + bt;
    out[i] = sigm(v);
  }
}

extern "C" void kernel_launch(void* const* d_in, const int* in_sizes, int n_in,
                              void* d_out, int out_size, void* d_ws, size_t ws_size,
                              hipStream_t stream) {
  const float* x      = (const float*)d_in[0];
  const float* h_ext  = (const float*)d_in[1];
  const float* c_ext  = (const float*)d_in[2];
  const float* grid_h = (const float*)d_in[3];
  const float* grid_c = (const float*)d_in[4];
  const float* Wh     = (const float*)d_in[5];
  const float* bh     = (const float*)d_in[6];
  const float* Wc     = (const float*)d_in[7];
  const float* bc     = (const float*)d_in[8];
  const float* W_ih   = (const float*)d_in[9];
  const float* W_hh   = (const float*)d_in[10];
  const float* b_ih   = (const float*)d_in[11];
  const float* b_hh   = (const float*)d_in[12];
  const float* W1     = (const float*)d_in[13];
  const float* b1     = (const float*)d_in[14];
  const float* W2     = (const float*)d_in[15];
  const float* b2     = (const float*)d_in[16];
  const float* gamma  = (const float*)d_in[17];
  const float* beta   = (const float*)d_in[18];

  float* out = (float*)d_out;
  float* fh_out = out + 8192;
  float* fc_out = fh_out + BH;
  float* gh_out = fc_out + BH;   // new_gh [8][B][H] f32 (read as A by later diags)
  float* gc_out = gh_out + 8 * BH;

  char* ws = (char*)d_ws;
  size_t off = 0;
  auto alloc = [&](size_t bytes) {
    char* p = ws + off;
    off = (off + bytes + 255) & ~(size_t)255;
    return p;
  };
  unsigned short* whB   = (unsigned short*)alloc(8ull * 512 * 1536 * 2);
  unsigned short* wcB   = (unsigned short*)alloc(8ull * 512 * 1536 * 2);
  unsigned short* whhB  = (unsigned short*)alloc(8ull * 2048 * 512 * 2);
  unsigned short* w1B   = (unsigned short*)alloc(256ull * 1024 * 2);
  unsigned short* pcB   = (unsigned short*)alloc(8 * BH * 2);
  unsigned short* phB   = (unsigned short*)alloc(8 * BH * 2);
  unsigned short* finalB = (unsigned short*)alloc((size_t)B_SZ * 1024 * 2);
  unsigned short* hidB   = (unsigned short*)alloc((size_t)B_SZ * 256 * 2);
  float*          outlin = (float*)alloc((size_t)B_SZ * 4);

  // allow big dynamic LDS (idempotent, capture-safe)
  hipFuncSetAttribute((const void*)gates_k,
                      hipFuncAttributeMaxDynamicSharedMemorySize, 131072);
  hipFuncSetAttribute((const void*)pgemm256_k,
                      hipFuncAttributeMaxDynamicSharedMemorySize, 98304);

  // ---- 1 launch: weight f32->bf16 conversions only ----
  {
    CvtArgs ca;
    long n4[4] = {8L * 512 * 1536 / 4, 8L * 512 * 1536 / 4,
                  8L * 2048 * 512 / 4, 256L * 1024 / 4};
    const float* srcs[4] = {Wh, Wc, W_hh, W1};
    unsigned short* dsts[4] = {whB, wcB, whhB, w1B};
    ca.start[0] = 0;
    for (int q = 0; q < 8; ++q) {
      int qq = q < 4 ? q : 3;
      ca.s[q] = (const float4*)srcs[qq];
      ca.d[q] = (uint2*)dsts[qq];
      ca.start[q + 1] = ca.start[q] + (q < 4 ? n4[q] : 0);
    }
    convert_many<<<2048, 256, 0, stream>>>(ca);
  }

  // fused-K ph/pc GEMM for a diagonal's cells (128x256 2-phase, f32 A direct)
  auto launch_p = [&](const int* cells, int n) {
    P8Args pa = {};
    pa.ldB = 1536; pa.outStride = 512;
    for (int q = 0; q < n; ++q) {
      int k = cells[q];
      int i = k >> 1, jj = k & 1;
      P8Job& jh = pa.j[2 * q];
      P8Job& jc = pa.j[2 * q + 1];
      jh = P8Job{}; jc = P8Job{};
      int ns = 0;
      if (k == 0) {  // ext is "left" for cell 0
        jh.A[ns] = h_ext; jc.A[ns] = c_ext;
        jh.co[ns] = 0; jc.co[ns] = 0; ns++;
      } else if (jj > 0) {  // left neighbor = cell k-1
        jh.A[ns] = gh_out + (size_t)(k - 1) * BH;
        jc.A[ns] = gc_out + (size_t)(k - 1) * BH;
        jh.co[ns] = 0; jc.co[ns] = 0; ns++;
      }
      if (i > 0) {  // up neighbor = cell k-2
        jh.A[ns] = gh_out + (size_t)(k - 2) * BH;
        jc.A[ns] = gc_out + (size_t)(k - 2) * BH;
        jh.co[ns] = 512; jc.co[ns] = 512; ns++;
      }
      jh.A[ns] = grid_h + (size_t)k * BH;
      jc.A[ns] = grid_c + (size_t)k * BH;
      jh.co[ns] = 1024; jc.co[ns] = 1024; ns++;
      jh.nseg = ns; jc.nseg = ns;
      jh.B = whB + (size_t)k * 512 * 1536; jh.bias = bh + k * 512;
      jc.B = wcB + (size_t)k * 512 * 1536; jc.bias = bc + k * 512;
      jh.outBf = phB + (size_t)k * BH;
      jc.outBf = pcB + (size_t)k * BH;
    }
    pgemm256_k<<<dim3(2, 64, 2 * n), 512, 98304, stream>>>(pa);
  };

  auto launch_gates = [&](const int* cells, int n) {
    GArgs ga = {};
    ga.x = x; ga.W_ih = W_ih; ga.b_ih = b_ih; ga.b_hh = b_hh;
    ga.h_ext = h_ext; ga.c_ext = c_ext;
    ga.fh = fh_out; ga.fc = fc_out; ga.finalB = finalB;
    for (int q = 0; q < n; ++q) {
      int k = cells[q];
      GJob& j = ga.j[q];
      j.ph = phB + (size_t)k * BH;
      j.Whh = whhB + (size_t)k * 2048 * 512;
      j.pc = pcB + (size_t)k * BH;
      j.gh = gh_out + (size_t)k * BH;
      j.gc = gc_out + (size_t)k * BH;
      j.cell = k; j.last = (k == 7);
    }
    gates_k<<<dim3(8, 32, n), 512, 131072, stream>>>(ga);
  };

  const int diags[5][2] = {{0, -1}, {1, 2}, {3, 4}, {5, 6}, {7, -1}};
  const int dn[5] = {1, 2, 2, 2, 1};
  for (int d = 0; d < 5; ++d) {
    launch_p(diags[d], dn[d]);
    launch_gates(diags[d], dn[d]);
  }

  // FC1: [8192x1024] @ W1[256x1024]^T + b1, relu -> bf16 (legacy 128^2 kernel)
  {
    PArgs pa = {};
    pa.ldA = 1024; pa.ldB = 1024; pa.outStride = 256;
    PJob& j = pa.j[0];
    j = PJob{};
    j.A[0] = finalB; j.co[0] = 0;
    j.A[1] = finalB + 512; j.co[1] = 512;
    j.nseg = 2; j.relu = 1;
    j.B = w1B; j.bias = b1; j.outBf = hidB;
    pgemm_k<<<dim3(2, 64, 1), 256, 0, stream>>>(pa);
  }

  fc2_kernel<<<2048, 256, 0, stream>>>(hidB, W2, b2, outlin);
  bn_kernel<<<1, 1024, 0, stream>>>(outlin, gamma, beta, out);
}

// Round 12
// 652.661 us; speedup vs baseline: 1.1501x; 1.1501x over previous
//
#include <hip/hip_runtime.h>
#include <stdint.h>

#define B_SZ 8192
static const size_t BH = (size_t)B_SZ * 512;

typedef short bfrag8 __attribute__((ext_vector_type(8)));
typedef float f32x4 __attribute__((ext_vector_type(4)));

__device__ __forceinline__ unsigned short f2bf(float f) {
  union { float f; uint32_t u; } c; c.f = f;
  uint32_t u = c.u;
  uint32_t r = (u + 0x7FFFu + ((u >> 16) & 1u)) >> 16;
  return (unsigned short)r;
}
__device__ __forceinline__ float bf2f(unsigned short u) {
  union { uint32_t u; float f; } c; c.u = ((uint32_t)u) << 16;
  return c.f;
}
// packed f32x2 -> bf16x2 (RNE), single HW instruction
__device__ __forceinline__ uint32_t pk2(float a, float b) {
  uint32_t r;
  asm("v_cvt_pk_bf16_f32 %0, %1, %2" : "=v"(r) : "v"(a), "v"(b));
  return r;
}
__device__ __forceinline__ float sigm(float x) { return 1.0f / (1.0f + __expf(-x)); }
__device__ __forceinline__ float tanh_fast(float x) {
  float cx = fminf(fmaxf(x, -15.0f), 15.0f);
  float e = __expf(2.0f * cx);
  return (e - 1.0f) / (e + 1.0f);
}

__device__ __forceinline__ void gload16(const void* g, void* l) {
  __builtin_amdgcn_global_load_lds(
      (const __attribute__((address_space(1))) void*)g,
      (__attribute__((address_space(3))) void*)l, 16, 0, 0);
}

// bijective XCD-chunk swizzle (m204)
__device__ __forceinline__ void xcd_swizzle(int& bx, int& by, int& bz) {
  int nx = gridDim.x, ny = gridDim.y, nz = gridDim.z;
  int nwg = nx * ny * nz;
  int id = blockIdx.x + nx * (blockIdx.y + ny * blockIdx.z);
  int q = nwg >> 3, r = nwg & 7;
  int xcd = id & 7, lin = id >> 3;
  int swz = (xcd < r ? xcd * (q + 1) : r * (q + 1) + (xcd - r) * q) + lin;
  bx = swz % nx; swz /= nx;
  by = swz % ny; bz = swz / ny;
}

// shared job structs for the f32-A ph/pc GEMMs
struct P8Job {
  const float* A[3];
  int co[3];
  int nseg;
  const unsigned short* B;
  const float* bias;
  unsigned short* outBf;
};
struct P8Args {
  P8Job j[4];
  int ldB, outStride;
};

// ======== ph/pc GEMM (n=2 diags): 256x256 tile, 2-phase, 8 waves ============
// R10-proven. LDS 128KB: A dbuf @0/32K, B dbuf @64K/96K.
__global__ __launch_bounds__(512, 1) void pgemm256_k(P8Args pa) {
  extern __shared__ char lds[];
  int bx, by, bz;
  xcd_swizzle(bx, by, bz);
  const P8Job jb = pa.j[bz];
  const int tid = threadIdx.x;
  const int lane = tid & 63;
  const int wv = tid >> 6;
  const int wr = wv >> 2, wc = wv & 3;
  const int m0 = by * 256;

  int rowS[4], cgS[4];
  const char* bPtr[4];
#pragma unroll
  for (int q = 0; q < 4; ++q) {
    int cl = q * 512 + tid;
    int row = cl >> 3, cs = cl & 7;
    cgS[q] = cs ^ (row & 7);
    rowS[q] = row;
    bPtr[q] = (const char*)jb.B + (size_t)(bx * 256 + row) * pa.ldB * 2;
  }

  auto loadA = [&](int t, float4* a0, float4* a1) {
    int seg = t >> 3, k0 = (t & 7) << 6;
    const float* Ab = jb.A[seg];
#pragma unroll
    for (int q = 0; q < 4; ++q) {
      const float4* p = (const float4*)(Ab + (size_t)(m0 + rowS[q]) * 512 + k0 +
                                        cgS[q] * 8);
      a0[q] = p[0];
      a1[q] = p[1];
    }
  };
  auto stageB = [&](int t, int buf) {
    int seg = t >> 3, k0 = (t & 7) << 6;
    int coB = (jb.co[seg] + k0) * 2;
    char* Bb = lds + 65536 + buf * 32768;
#pragma unroll
    for (int q = 0; q < 4; ++q)
      gload16(bPtr[q] + coB + cgS[q] * 16, Bb + (q * 512 + tid) * 16);
  };
  auto writeA = [&](const float4* a0, const float4* a1, int buf) {
    char* Ab = lds + buf * 32768;
#pragma unroll
    for (int q = 0; q < 4; ++q) {
      uint4 w;
      w.x = pk2(a0[q].x, a0[q].y);
      w.y = pk2(a0[q].z, a0[q].w);
      w.z = pk2(a1[q].x, a1[q].y);
      w.w = pk2(a1[q].z, a1[q].w);
      *(uint4*)(Ab + (q * 512 + tid) * 16) = w;
    }
  };

  f32x4 acc[8][4];
#pragma unroll
  for (int a = 0; a < 8; ++a)
#pragma unroll
    for (int b = 0; b < 4; ++b) acc[a][b] = f32x4{0.f, 0.f, 0.f, 0.f};

  const int nt = jb.nseg * 8;

  {
    float4 a0[4], a1[4];
    loadA(0, a0, a1);
    stageB(0, 0);
    writeA(a0, a1, 0);
  }
  __syncthreads();

  int cur = 0;
  for (int t = 0; t < nt; ++t) {
    float4 a0[4], a1[4];
    const bool more = (t + 1 < nt);
    if (more) {
      loadA(t + 1, a0, a1);   // issue early (T14)
      stageB(t + 1, cur ^ 1);
    }
    const char* As = lds + cur * 32768;
    const char* Bs = lds + 65536 + cur * 32768;
    bfrag8 bfr[4][2];
#pragma unroll
    for (int nf = 0; nf < 4; ++nf)
#pragma unroll
      for (int ks = 0; ks < 2; ++ks) {
        int row = wc * 64 + nf * 16 + (lane & 15);
        bfr[nf][ks] = *(const bfrag8*)(Bs + row * 128 +
                                       (((ks * 4 + (lane >> 4)) ^ (row & 7)) * 16));
      }
#pragma unroll
    for (int mf = 0; mf < 8; ++mf) {
      bfrag8 af[2];
#pragma unroll
      for (int ks = 0; ks < 2; ++ks) {
        int row = wr * 128 + mf * 16 + (lane & 15);
        af[ks] = *(const bfrag8*)(As + row * 128 +
                                  (((ks * 4 + (lane >> 4)) ^ (row & 7)) * 16));
      }
#pragma unroll
      for (int nf = 0; nf < 4; ++nf)
#pragma unroll
        for (int ks = 0; ks < 2; ++ks)
          acc[mf][nf] = __builtin_amdgcn_mfma_f32_16x16x32_bf16(
              af[ks], bfr[nf][ks], acc[mf][nf], 0, 0, 0);
    }
    if (more) writeA(a0, a1, cur ^ 1);  // write late: HBM latency hid under MFMA
    __syncthreads();
    cur ^= 1;
  }

  const int c4 = lane & 15;
  const int r4 = lane >> 4;
  const int n0 = bx * 256;
#pragma unroll
  for (int nf = 0; nf < 4; ++nf) {
    int colg = n0 + wc * 64 + nf * 16 + c4;
    float bv = jb.bias[colg];
#pragma unroll
    for (int mf = 0; mf < 8; ++mf)
#pragma unroll
      for (int r = 0; r < 4; ++r) {
        int rowg = m0 + wr * 128 + mf * 16 + r4 * 4 + r;
        jb.outBf[(size_t)rowg * pa.outStride + colg] = f2bf(acc[mf][nf][r] + bv);
      }
  }
}

// ======== ph/pc GEMM (n=1 diags): 128x256 tile, fills all 256 CUs ===========
// LDS 96KB: A dbuf @0/16K, B dbuf @32K/64K.
__global__ __launch_bounds__(512, 1) void pgemm128_k(P8Args pa) {
  extern __shared__ char lds[];
  int bx, by, bz;
  xcd_swizzle(bx, by, bz);
  const P8Job jb = pa.j[bz];
  const int tid = threadIdx.x;
  const int lane = tid & 63;
  const int wv = tid >> 6;
  const int wr = wv >> 2, wc = wv & 3;
  const int m0 = by * 128;

  int cgB[4];
  const char* bPtr[4];
#pragma unroll
  for (int q = 0; q < 4; ++q) {
    int cl = q * 512 + tid;
    int row = cl >> 3, cs = cl & 7;
    cgB[q] = cs ^ (row & 7);
    bPtr[q] = (const char*)jb.B + (size_t)(bx * 256 + row) * pa.ldB * 2;
  }
  int rowA[2], cgA[2];
#pragma unroll
  for (int q = 0; q < 2; ++q) {
    int cl = q * 512 + tid;
    int row = cl >> 3, cs = cl & 7;
    cgA[q] = cs ^ (row & 7);
    rowA[q] = row;
  }

  auto stageB = [&](int t, int buf) {
    int seg = t >> 3, k0 = (t & 7) << 6;
    int coB = (jb.co[seg] + k0) * 2;
    char* Bb = lds + 32768 + buf * 32768;
#pragma unroll
    for (int q = 0; q < 4; ++q)
      gload16(bPtr[q] + coB + cgB[q] * 16, Bb + (q * 512 + tid) * 16);
  };
  auto loadA = [&](int t, float4* a0, float4* a1) {
    int seg = t >> 3, k0 = (t & 7) << 6;
    const float* Ab = jb.A[seg];
#pragma unroll
    for (int q = 0; q < 2; ++q) {
      const float4* p = (const float4*)(Ab + (size_t)(m0 + rowA[q]) * 512 + k0 +
                                        cgA[q] * 8);
      a0[q] = p[0];
      a1[q] = p[1];
    }
  };
  auto writeA = [&](const float4* a0, const float4* a1, int buf) {
    char* Ab = lds + buf * 16384;
#pragma unroll
    for (int q = 0; q < 2; ++q) {
      uint4 w;
      w.x = pk2(a0[q].x, a0[q].y);
      w.y = pk2(a0[q].z, a0[q].w);
      w.z = pk2(a1[q].x, a1[q].y);
      w.w = pk2(a1[q].z, a1[q].w);
      *(uint4*)(Ab + (q * 512 + tid) * 16) = w;
    }
  };

  f32x4 acc[4][4];
#pragma unroll
  for (int a = 0; a < 4; ++a)
#pragma unroll
    for (int b = 0; b < 4; ++b) acc[a][b] = f32x4{0.f, 0.f, 0.f, 0.f};

  const int nt = jb.nseg * 8;

  {
    float4 a0[2], a1[2];
    stageB(0, 0);
    loadA(0, a0, a1);
    writeA(a0, a1, 0);
  }
  __syncthreads();

  int cur = 0;
  for (int t = 0; t < nt; ++t) {
    float4 a0[2], a1[2];
    const bool more = (t + 1 < nt);
    if (more) {
      stageB(t + 1, cur ^ 1);
      loadA(t + 1, a0, a1);
    }
    const char* As = lds + cur * 16384;
    const char* Bs = lds + 32768 + cur * 32768;
    bfrag8 bfr[4][2];
#pragma unroll
    for (int nf = 0; nf < 4; ++nf)
#pragma unroll
      for (int ks = 0; ks < 2; ++ks) {
        int row = wc * 64 + nf * 16 + (lane & 15);
        bfr[nf][ks] = *(const bfrag8*)(Bs + row * 128 +
                                       (((ks * 4 + (lane >> 4)) ^ (row & 7)) * 16));
      }
#pragma unroll
    for (int mf = 0; mf < 4; ++mf) {
      bfrag8 af[2];
#pragma unroll
      for (int ks = 0; ks < 2; ++ks) {
        int row = wr * 64 + mf * 16 + (lane & 15);
        af[ks] = *(const bfrag8*)(As + row * 128 +
                                  (((ks * 4 + (lane >> 4)) ^ (row & 7)) * 16));
      }
#pragma unroll
      for (int nf = 0; nf < 4; ++nf)
#pragma unroll
        for (int ks = 0; ks < 2; ++ks)
          acc[mf][nf] = __builtin_amdgcn_mfma_f32_16x16x32_bf16(
              af[ks], bfr[nf][ks], acc[mf][nf], 0, 0, 0);
    }
    if (more) writeA(a0, a1, cur ^ 1);
    __syncthreads();
    cur ^= 1;
  }

  const int c4 = lane & 15;
  const int r4 = lane >> 4;
  const int n0 = bx * 256;
#pragma unroll
  for (int nf = 0; nf < 4; ++nf) {
    int colg = n0 + wc * 64 + nf * 16 + c4;
    float bv = jb.bias[colg];
#pragma unroll
    for (int mf = 0; mf < 4; ++mf)
#pragma unroll
      for (int r = 0; r < 4; ++r) {
        int rowg = m0 + wr * 64 + mf * 16 + r4 * 4 + r;
        jb.outBf[(size_t)rowg * pa.outStride + colg] = f2bf(acc[mf][nf][r] + bv);
      }
  }
}

// ------- gates GEMM: 256x256 tile, 2-phase, 8 waves, dbuf LDS (R10 exact) ---
struct GJob {
  const unsigned short* ph;
  const unsigned short* Whh;
  const unsigned short* pc;  // bf16
  float* gh; float* gc;
  int cell, last;
};
struct GArgs {
  GJob j[2];
  const float* x;
  const float* W_ih; const float* b_ih; const float* b_hh;
  const float* h_ext; const float* c_ext;
  float* fh; float* fc;
  unsigned short* finalB;
};

__global__ __launch_bounds__(512, 2) void gates_k(GArgs ga) {
  extern __shared__ char lds[];
  int bx, by, bz;
  xcd_swizzle(bx, by, bz);
  const GJob jb = ga.j[bz];
  const int tid = threadIdx.x;
  const int lane = tid & 63;
  const int wv = tid >> 6;
  const int wr = wv >> 2;
  const int wc = wv & 3;
  const int m0 = by * 256;

  int rowS[4], cgS[4];
  const char* bPtr[4];
#pragma unroll
  for (int q = 0; q < 4; ++q) {
    int cl = q * 512 + tid;
    int row = cl >> 3, cs = cl & 7;
    cgS[q] = cs ^ (row & 7);
    rowS[q] = row;
    int browG = ((row >> 4) & 3) * 512 + bx * 64 + ((row >> 6) << 4) + (row & 15);
    bPtr[q] = (const char*)jb.Whh + (size_t)browG * 512 * 2;
  }

  auto stage = [&](int t, int buf) {
    int k0 = t << 6;
    char* Ab = lds + buf * 32768;
    char* Bb = lds + 65536 + buf * 32768;
#pragma unroll
    for (int q = 0; q < 4; ++q)
      gload16((const char*)jb.ph + ((size_t)(m0 + rowS[q]) * 512 + k0) * 2 + cgS[q] * 16,
              Ab + (q * 512 + tid) * 16);
#pragma unroll
    for (int q = 0; q < 4; ++q)
      gload16(bPtr[q] + k0 * 2 + cgS[q] * 16, Bb + (q * 512 + tid) * 16);
  };

  f32x4 acc[8][4];
#pragma unroll
  for (int a = 0; a < 8; ++a)
#pragma unroll
    for (int b = 0; b < 4; ++b) acc[a][b] = f32x4{0.f, 0.f, 0.f, 0.f};

  stage(0, 0);
  asm volatile("s_waitcnt vmcnt(0)" ::: "memory");
  __builtin_amdgcn_s_barrier();
  asm volatile("" ::: "memory");

  int cur = 0;
  for (int t = 0; t < 8; ++t) {
    if (t + 1 < 8) stage(t + 1, cur ^ 1);
    const char* As = lds + cur * 32768;
    const char* Bs = lds + 65536 + cur * 32768;
    bfrag8 bfr[4][2];
#pragma unroll
    for (int nf = 0; nf < 4; ++nf)
#pragma unroll
      for (int ks = 0; ks < 2; ++ks) {
        int row = wc * 64 + nf * 16 + (lane & 15);
        bfr[nf][ks] = *(const bfrag8*)(Bs + row * 128 +
                                       (((ks * 4 + (lane >> 4)) ^ (row & 7)) * 16));
      }
#pragma unroll
    for (int mf = 0; mf < 8; ++mf) {
      bfrag8 af[2];
#pragma unroll
      for (int ks = 0; ks < 2; ++ks) {
        int row = wr * 128 + mf * 16 + (lane & 15);
        af[ks] = *(const bfrag8*)(As + row * 128 +
                                  (((ks * 4 + (lane >> 4)) ^ (row & 7)) * 16));
      }
#pragma unroll
      for (int nf = 0; nf < 4; ++nf)
#pragma unroll
        for (int ks = 0; ks < 2; ++ks)
          acc[mf][nf] = __builtin_amdgcn_mfma_f32_16x16x32_bf16(
              af[ks], bfr[nf][ks], acc[mf][nf], 0, 0, 0);
    }
    asm volatile("s_waitcnt vmcnt(0)" ::: "memory");
    __builtin_amdgcn_s_barrier();
    asm volatile("" ::: "memory");
    cur ^= 1;
  }

  const int c4 = lane & 15;
  const int r4 = lane >> 4;
  int hcol = bx * 64 + wc * 16 + c4;
  const float* Wih = ga.W_ih + jb.cell * 2048;
  const float* bih = ga.b_ih + jb.cell * 2048;
  const float* bhh = ga.b_hh + jb.cell * 2048;
  float wih[4], gb[4];
#pragma unroll
  for (int q = 0; q < 4; ++q) {
    wih[q] = Wih[q * 512 + hcol];
    gb[q] = bih[q * 512 + hcol] + bhh[q * 512 + hcol];
  }
#pragma unroll
  for (int mf = 0; mf < 8; ++mf)
#pragma unroll
    for (int r = 0; r < 4; ++r) {
      int b = m0 + wr * 128 + mf * 16 + r4 * 4 + r;
      float xi = ga.x[b * 8 + jb.cell];
      float vi = acc[mf][0][r] + xi * wih[0] + gb[0];
      float vf = acc[mf][1][r] + xi * wih[1] + gb[1];
      float vg = acc[mf][2][r] + xi * wih[2] + gb[2];
      float vo = acc[mf][3][r] + xi * wih[3] + gb[3];
      size_t o = (size_t)b * 512 + hcol;
      float pcv = bf2f(jb.pc[o]);
      float cn = sigm(vf) * pcv + sigm(vi) * tanh_fast(vg);
      float hn = sigm(vo) * tanh_fast(cn);
      jb.gh[o] = hn;
      jb.gc[o] = cn;
      if (jb.last) {
        float fh = hn + ga.h_ext[o];
        float fc = cn + ga.c_ext[o];
        ga.fh[o] = fh;
        ga.fc[o] = fc;
        ga.finalB[(size_t)b * 1024 + hcol] = f2bf(fh);
        ga.finalB[(size_t)b * 1024 + 512 + hcol] = f2bf(fc);
      }
    }
}

// ================= legacy 128x128 2-barrier GEMM (FC1 only) =================
struct PJob {
  const void* A[3];
  int co[3];
  int nseg, relu;
  const unsigned short* B;
  const float* bias;
  unsigned short* outBf;
};
struct PArgs {
  PJob j[8];
  int ldA, ldB, outStride;
};

__global__ __launch_bounds__(256, 4) void pgemm_k(PArgs pa) {
  __shared__ __align__(16) char As[16384];
  __shared__ __align__(16) char Bs[16384];
  int bx, by, bz;
  xcd_swizzle(bx, by, bz);
  const PJob jb = pa.j[bz];
  const int tid = threadIdx.x;
  const int lane = tid & 63;
  const int wv = tid >> 6;
  const int wr = wv >> 1, wc = wv & 1;
  const int m0 = by * 128;

  int rowA[4], cg[4];
  const char* browPtr[4];
#pragma unroll
  for (int q = 0; q < 4; ++q) {
    int cl = q * 256 + tid;
    int row = cl >> 3, cs = cl & 7;
    cg[q] = cs ^ (row & 7);
    rowA[q] = row;
    browPtr[q] = (const char*)jb.B + (size_t)(bx * 128 + row) * pa.ldB * 2;
  }

  f32x4 acc[4][4];
#pragma unroll
  for (int a = 0; a < 4; ++a)
#pragma unroll
    for (int b = 0; b < 4; ++b) acc[a][b] = f32x4{0.f, 0.f, 0.f, 0.f};

  for (int s = 0; s < jb.nseg; ++s) {
    const char* Abase = (const char*)jb.A[s];
    const int coB = jb.co[s] * 2;
    for (int k0 = 0; k0 < 512; k0 += 64) {
#pragma unroll
      for (int q = 0; q < 4; ++q)
        gload16(Abase + ((size_t)(m0 + rowA[q]) * pa.ldA + k0) * 2 + cg[q] * 16,
                As + (q * 256 + tid) * 16);
#pragma unroll
      for (int q = 0; q < 4; ++q)
        gload16(browPtr[q] + coB + k0 * 2 + cg[q] * 16,
                Bs + (q * 256 + tid) * 16);
      __syncthreads();
#pragma unroll
      for (int ks = 0; ks < 2; ++ks) {
        bfrag8 af[4], bfr[4];
#pragma unroll
        for (int mf = 0; mf < 4; ++mf) {
          int row = wr * 64 + mf * 16 + (lane & 15);
          af[mf] = *(const bfrag8*)(As + row * 128 +
                                    ((ks * 4 + (lane >> 4)) ^ (row & 7)) * 16);
        }
#pragma unroll
        for (int nf = 0; nf < 4; ++nf) {
          int row = wc * 64 + nf * 16 + (lane & 15);
          bfr[nf] = *(const bfrag8*)(Bs + row * 128 +
                                     ((ks * 4 + (lane >> 4)) ^ (row & 7)) * 16);
        }
#pragma unroll
        for (int mf = 0; mf < 4; ++mf)
#pragma unroll
          for (int nf = 0; nf < 4; ++nf)
            acc[mf][nf] = __builtin_amdgcn_mfma_f32_16x16x32_bf16(
                af[mf], bfr[nf], acc[mf][nf], 0, 0, 0);
      }
      __syncthreads();
    }
  }

  const int c4 = lane & 15;
  const int r4 = lane >> 4;
  const int n0 = bx * 128;
#pragma unroll
  for (int nf = 0; nf < 4; ++nf) {
    int colg = n0 + wc * 64 + nf * 16 + c4;
    float bv = jb.bias[colg];
#pragma unroll
    for (int mf = 0; mf < 4; ++mf)
#pragma unroll
      for (int r = 0; r < 4; ++r) {
        int rowg = m0 + wr * 64 + mf * 16 + r4 * 4 + r;
        size_t o = (size_t)rowg * pa.outStride + colg;
        float v = acc[mf][nf][r] + bv;
        if (jb.relu) v = fmaxf(v, 0.0f);
        jb.outBf[o] = f2bf(v);
      }
  }
}

// ---------------- one-shot f32 -> bf16 converter (weights only) -------------
struct CvtArgs {
  const float4* s[8];
  uint2* d[8];
  long start[9];
};
__global__ __launch_bounds__(256) void convert_many(CvtArgs ca) {
  long total = ca.start[8];
  long stride = (long)gridDim.x * blockDim.x;
  for (long idx = (long)blockIdx.x * blockDim.x + threadIdx.x; idx < total;
       idx += stride) {
    int jb = 0;
#pragma unroll
    for (int q = 1; q < 8; ++q) jb += (idx >= ca.start[q]) ? 1 : 0;
    long local = idx - ca.start[jb];
    float4 v = ca.s[jb][local];
    uint2 o;
    o.x = (uint32_t)f2bf(v.x) | ((uint32_t)f2bf(v.y) << 16);
    o.y = (uint32_t)f2bf(v.z) | ((uint32_t)f2bf(v.w) << 16);
    ca.d[jb][local] = o;
  }
}

__global__ __launch_bounds__(256)
void fc2_kernel(const unsigned short* hid, const float* W2, const float* b2,
                float* outlin) {
  int row = blockIdx.x * 4 + (threadIdx.x >> 6);
  int lane = threadIdx.x & 63;
  uint2 hv = ((const uint2*)(hid + (size_t)row * 256))[lane];
  float4 wv = ((const float4*)W2)[lane];
  float s = bf2f((unsigned short)(hv.x & 0xffffu)) * wv.x +
            bf2f((unsigned short)(hv.x >> 16)) * wv.y +
            bf2f((unsigned short)(hv.y & 0xffffu)) * wv.z +
            bf2f((unsigned short)(hv.y >> 16)) * wv.w;
#pragma unroll
  for (int o = 32; o > 0; o >>= 1) s += __shfl_down(s, o);
  if (lane == 0) outlin[row] = s + b2[0];
}

__global__ __launch_bounds__(1024)
void bn_kernel(const float* outlin, const float* gamma, const float* beta,
               float* out) {
  __shared__ float sred[16], sred2[16];
  __shared__ float smu, srs;
  float s = 0.f, s2 = 0.f;
  for (int i = threadIdx.x; i < 8192; i += 1024) {
    float v = outlin[i];
    s += v; s2 += v * v;
  }
#pragma unroll
  for (int o = 32; o > 0; o >>= 1) { s += __shfl_down(s, o); s2 += __shfl_down(s2, o); }
  if ((threadIdx.x & 63) == 0) { sred[threadIdx.x >> 6] = s; sred2[threadIdx.x >> 6] = s2; }
  __syncthreads();
  if (threadIdx.x == 0) {
    float S = 0.f, S2 = 0.f;
    for (int q = 0; q < 16; ++q) { S += sred[q]; S2 += sred2[q]; }
    float mu = S * (1.0f / 8192.0f);
    float var = S2 * (1.0f / 8192.0f) - mu * mu;
    smu = mu; srs = rsqrtf(var + 1e-5f);
  }
  __syncthreads();
  float gm = gamma[0], bt = beta[0];
  for (int i = threadIdx.x; i < 8192; i += 1024) {
    float v = (outlin[i] - smu) * srs * gm + bt;
    out[i] = sigm(v);
  }
}

extern "C" void kernel_launch(void* const* d_in, const int* in_sizes, int n_in,
                              void* d_out, int out_size, void* d_ws, size_t ws_size,
                              hipStream_t stream) {
  const float* x      = (const float*)d_in[0];
  const float* h_ext  = (const float*)d_in[1];
  const float* c_ext  = (const float*)d_in[2];
  const float* grid_h = (const float*)d_in[3];
  const float* grid_c = (const float*)d_in[4];
  const float* Wh     = (const float*)d_in[5];
  const float* bh     = (const float*)d_in[6];
  const float* Wc     = (const float*)d_in[7];
  const float* bc     = (const float*)d_in[8];
  const float* W_ih   = (const float*)d_in[9];
  const float* W_hh   = (const float*)d_in[10];
  const float* b_ih   = (const float*)d_in[11];
  const float* b_hh   = (const float*)d_in[12];
  const float* W1     = (const float*)d_in[13];
  const float* b1     = (const float*)d_in[14];
  const float* W2     = (const float*)d_in[15];
  const float* b2     = (const float*)d_in[16];
  const float* gamma  = (const float*)d_in[17];
  const float* beta   = (const float*)d_in[18];

  float* out = (float*)d_out;
  float* fh_out = out + 8192;
  float* fc_out = fh_out + BH;
  float* gh_out = fc_out + BH;   // new_gh [8][B][H] f32 (read as A by later diags)
  float* gc_out = gh_out + 8 * BH;

  char* ws = (char*)d_ws;
  size_t off = 0;
  auto alloc = [&](size_t bytes) {
    char* p = ws + off;
    off = (off + bytes + 255) & ~(size_t)255;
    return p;
  };
  unsigned short* whB   = (unsigned short*)alloc(8ull * 512 * 1536 * 2);
  unsigned short* wcB   = (unsigned short*)alloc(8ull * 512 * 1536 * 2);
  unsigned short* whhB  = (unsigned short*)alloc(8ull * 2048 * 512 * 2);
  unsigned short* w1B   = (unsigned short*)alloc(256ull * 1024 * 2);
  unsigned short* pcB   = (unsigned short*)alloc(8 * BH * 2);
  unsigned short* phB   = (unsigned short*)alloc(8 * BH * 2);
  unsigned short* finalB = (unsigned short*)alloc((size_t)B_SZ * 1024 * 2);
  unsigned short* hidB   = (unsigned short*)alloc((size_t)B_SZ * 256 * 2);
  float*          outlin = (float*)alloc((size_t)B_SZ * 4);

  // allow big dynamic LDS (idempotent, capture-safe)
  hipFuncSetAttribute((const void*)gates_k,
                      hipFuncAttributeMaxDynamicSharedMemorySize, 131072);
  hipFuncSetAttribute((const void*)pgemm256_k,
                      hipFuncAttributeMaxDynamicSharedMemorySize, 131072);
  hipFuncSetAttribute((const void*)pgemm128_k,
                      hipFuncAttributeMaxDynamicSharedMemorySize, 98304);

  // ---- 1 launch: weight f32->bf16 conversions only ----
  {
    CvtArgs ca;
    long n4[4] = {8L * 512 * 1536 / 4, 8L * 512 * 1536 / 4,
                  8L * 2048 * 512 / 4, 256L * 1024 / 4};
    const float* srcs[4] = {Wh, Wc, W_hh, W1};
    unsigned short* dsts[4] = {whB, wcB, whhB, w1B};
    ca.start[0] = 0;
    for (int q = 0; q < 8; ++q) {
      int qq = q < 4 ? q : 3;
      ca.s[q] = (const float4*)srcs[qq];
      ca.d[q] = (uint2*)dsts[qq];
      ca.start[q + 1] = ca.start[q] + (q < 4 ? n4[q] : 0);
    }
    convert_many<<<2048, 256, 0, stream>>>(ca);
  }

  // fused-K ph/pc GEMM for a diagonal's cells; 256^2 for n=2, 128x256 for n=1
  auto launch_p = [&](const int* cells, int n) {
    P8Args pa = {};
    pa.ldB = 1536; pa.outStride = 512;
    for (int q = 0; q < n; ++q) {
      int k = cells[q];
      int i = k >> 1, jj = k & 1;
      P8Job& jh = pa.j[2 * q];
      P8Job& jc = pa.j[2 * q + 1];
      jh = P8Job{}; jc = P8Job{};
      int ns = 0;
      if (k == 0) {  // ext is "left" for cell 0
        jh.A[ns] = h_ext; jc.A[ns] = c_ext;
        jh.co[ns] = 0; jc.co[ns] = 0; ns++;
      } else if (jj > 0) {  // left neighbor = cell k-1
        jh.A[ns] = gh_out + (size_t)(k - 1) * BH;
        jc.A[ns] = gc_out + (size_t)(k - 1) * BH;
        jh.co[ns] = 0; jc.co[ns] = 0; ns++;
      }
      if (i > 0) {  // up neighbor = cell k-2
        jh.A[ns] = gh_out + (size_t)(k - 2) * BH;
        jc.A[ns] = gc_out + (size_t)(k - 2) * BH;
        jh.co[ns] = 512; jc.co[ns] = 512; ns++;
      }
      jh.A[ns] = grid_h + (size_t)k * BH;
      jc.A[ns] = grid_c + (size_t)k * BH;
      jh.co[ns] = 1024; jc.co[ns] = 1024; ns++;
      jh.nseg = ns; jc.nseg = ns;
      jh.B = whB + (size_t)k * 512 * 1536; jh.bias = bh + k * 512;
      jc.B = wcB + (size_t)k * 512 * 1536; jc.bias = bc + k * 512;
      jh.outBf = phB + (size_t)k * BH;
      jc.outBf = pcB + (size_t)k * BH;
    }
    if (n == 1)
      pgemm128_k<<<dim3(2, 64, 2), 512, 98304, stream>>>(pa);
    else
      pgemm256_k<<<dim3(2, 32, 2 * n), 512, 131072, stream>>>(pa);
  };

  auto launch_gates = [&](const int* cells, int n) {
    GArgs ga = {};
    ga.x = x; ga.W_ih = W_ih; ga.b_ih = b_ih; ga.b_hh = b_hh;
    ga.h_ext = h_ext; ga.c_ext = c_ext;
    ga.fh = fh_out; ga.fc = fc_out; ga.finalB = finalB;
    for (int q = 0; q < n; ++q) {
      int k = cells[q];
      GJob& j = ga.j[q];
      j.ph = phB + (size_t)k * BH;
      j.Whh = whhB + (size_t)k * 2048 * 512;
      j.pc = pcB + (size_t)k * BH;
      j.gh = gh_out + (size_t)k * BH;
      j.gc = gc_out + (size_t)k * BH;
      j.cell = k; j.last = (k == 7);
    }
    gates_k<<<dim3(8, 32, n), 512, 131072, stream>>>(ga);
  };

  const int diags[5][2] = {{0, -1}, {1, 2}, {3, 4}, {5, 6}, {7, -1}};
  const int dn[5] = {1, 2, 2, 2, 1};
  for (int d = 0; d < 5; ++d) {
    launch_p(diags[d], dn[d]);
    launch_gates(diags[d], dn[d]);
  }

  // FC1: [8192x1024] @ W1[256x1024]^T + b1, relu -> bf16 (legacy 128^2 kernel)
  {
    PArgs pa = {};
    pa.ldA = 1024; pa.ldB = 1024; pa.outStride = 256;
    PJob& j = pa.j[0];
    j = PJob{};
    j.A[0] = finalB; j.co[0] = 0;
    j.A[1] = finalB + 512; j.co[1] = 512;
    j.nseg = 2; j.relu = 1;
    j.B = w1B; j.bias = b1; j.outBf = hidB;
    pgemm_k<<<dim3(2, 64, 1), 256, 0, stream>>>(pa);
  }

  fc2_kernel<<<2048, 256, 0, stream>>>(hidB, W2, b2, outlin);
  bn_kernel<<<1, 1024, 0, stream>>>(outlin, gamma, beta, out);
}